// Round 11
// baseline (638.467 us; speedup 1.0000x reference)
//
#include <hip/hip_runtime.h>
#include <math.h>

#define CC 128
#define HH 64
#define RBD 8
#define WDIM 512

typedef __attribute__((ext_vector_type(8))) short short8v;
typedef __attribute__((ext_vector_type(4))) float f32x4;

__device__ __forceinline__ float silu_f(float x) {
    return x / (1.0f + __expf(-x));
}

__device__ __forceinline__ unsigned short f2bf(float x) {
    unsigned int b = __float_as_uint(x);
    unsigned int r = (b + 0x7FFFu + ((b >> 16) & 1u)) >> 16;
    return (unsigned short)r;
}

__device__ __forceinline__ float bf2f(unsigned short u) {
    return __uint_as_float(((unsigned int)u) << 16);
}

// ---------------- transpose MLP weights + build MFMA B-fragments ----------------
__global__ void k_prep(const float* __restrict__ w0, const float* __restrict__ w1,
                       const float* __restrict__ w2, const float* __restrict__ w3,
                       float* __restrict__ w0T, float* __restrict__ w1T,
                       float* __restrict__ w2T, float* __restrict__ w3T,
                       unsigned short* __restrict__ w3bs) {
    int i = blockIdx.x * blockDim.x + threadIdx.x;
    if (i < 64 * 8) { int m = i / 8, k = i % 8; w0T[i] = w0[k * 64 + m]; }
    if (i < 64 * 64) { int m = i / 64, k = i % 64; w1T[i] = w1[k * 64 + m]; w2T[i] = w2[k * 64 + m]; }
    if (i < 512 * 64) { int j = i / 64, k = i % 64; w3T[i] = w3[k * 512 + j]; }
    if (i < 32768) {
        int t = i >> 10, ch = (i >> 9) & 1, lane = (i >> 3) & 63, j = i & 7;
        int k = ch * 32 + 8 * (lane >> 4) + j;
        int n = t * 16 + (lane & 15);
        w3bs[i] = f2bf(w3[k * 512 + n]);
    }
}

// ---------------- CSR build ----------------
__global__ void k_hist(const int* __restrict__ rcv, int* __restrict__ deg, int E_) {
    int e = blockIdx.x * blockDim.x + threadIdx.x;
    if (e < E_) atomicAdd(&deg[rcv[e]], 1);
}

__global__ __launch_bounds__(1024) void k_scan(const int* __restrict__ deg,
                                               int* __restrict__ off, int N) {
    __shared__ int s[1024];
    int t = threadIdx.x;
    int b = t * 4;
    int a0 = (b + 0 < N) ? deg[b + 0] : 0;
    int a1 = (b + 1 < N) ? deg[b + 1] : 0;
    int a2 = (b + 2 < N) ? deg[b + 2] : 0;
    int a3 = (b + 3 < N) ? deg[b + 3] : 0;
    int part = a0 + a1 + a2 + a3;
    s[t] = part;
    __syncthreads();
    for (int d = 1; d < 1024; d <<= 1) {
        int v = (t >= d) ? s[t - d] : 0;
        __syncthreads();
        s[t] += v;
        __syncthreads();
    }
    int excl = s[t] - part;
    if (b + 0 <= N) off[b + 0] = excl;
    if (b + 1 <= N) off[b + 1] = excl + a0;
    if (b + 2 <= N) off[b + 2] = excl + a0 + a1;
    if (b + 3 <= N) off[b + 3] = excl + a0 + a1 + a2;
}

__global__ void k_scatter(const int* __restrict__ rcv, const int* __restrict__ off,
                          int* __restrict__ cur, int* __restrict__ elist, int E_) {
    int e = blockIdx.x * blockDim.x + threadIdx.x;
    if (e < E_) {
        int r = rcv[e];
        int p = atomicAdd(&cur[r], 1);
        elist[off[r] + p] = e;
    }
}

// ---------------- edge meta: permuted unit vectors + senders ----------------
__global__ void k_emeta(const int* __restrict__ elist, const int* __restrict__ snd,
                        const float* __restrict__ evec,
                        float4* __restrict__ up, int* __restrict__ sp, int E_) {
    int p = blockIdx.x * blockDim.x + threadIdx.x;
    if (p >= E_) return;
    int e = elist[p];
    float e0 = evec[(size_t)e * 3 + 0];
    float e1 = evec[(size_t)e * 3 + 1];
    float e2 = evec[(size_t)e * 3 + 2];
    float rn = sqrtf(e0 * e0 + e1 * e1 + e2 * e2);
    float inv = 1.0f / fmaxf(rn, 1e-12f);
    up[p] = make_float4(e0 * inv, e1 * inv, e2 * inv, 0.f);
    sp[p] = snd[e];
}

// ---------------- node linear (planar y1: [3][N][C]) ----------------
__global__ __launch_bounds__(128) void k_node_lin(
    const float* __restrict__ xs, const float* __restrict__ xv,
    const float* __restrict__ W10, const float* __restrict__ W11,
    float* __restrict__ y0, float* __restrict__ y1, int N) {
    const int d = threadIdx.x;
    const int n0 = blockIdx.x * 4;
    const int NP = N * CC;
    const float inv_c = 0.08838834764831845f;
    float a0[4] = {0.f, 0.f, 0.f, 0.f};
    float av[4][3] = {};
    #pragma unroll 4
    for (int c = 0; c < CC; c++) {
        float w10 = W10[c * CC + d];
        float w11 = W11[c * CC + d];
        #pragma unroll
        for (int n = 0; n < 4; n++) {
            a0[n] += xs[(n0 + n) * CC + c] * w10;
            #pragma unroll
            for (int i = 0; i < 3; i++)
                av[n][i] += xv[((n0 + n) * CC + c) * 3 + i] * w11;
        }
    }
    #pragma unroll
    for (int n = 0; n < 4; n++) {
        y0[(n0 + n) * CC + d] = a0[n] * inv_c;
        #pragma unroll
        for (int i = 0; i < 3; i++)
            y1[i * NP + (n0 + n) * CC + d] = av[n][i] * inv_c;
    }
}

// ---------------- shared MLP body: h2 into a[16] ----------------
__device__ __forceinline__ void layer64(const float4* a, float4* b,
                                        const float* __restrict__ W) {
    #pragma unroll
    for (int m = 0; m < 16; m++) {
        float s0 = 0.f, s1 = 0.f, s2 = 0.f, s3 = 0.f;
        const float* w0p = W + (4 * m + 0) * 64;
        const float* w1p = W + (4 * m + 1) * 64;
        const float* w2p = W + (4 * m + 2) * 64;
        const float* w3p = W + (4 * m + 3) * 64;
        #pragma unroll
        for (int k = 0; k < 16; k++) {
            float4 av = a[k];
            s0 += av.x * w0p[4 * k + 0] + av.y * w0p[4 * k + 1] + av.z * w0p[4 * k + 2] + av.w * w0p[4 * k + 3];
            s1 += av.x * w1p[4 * k + 0] + av.y * w1p[4 * k + 1] + av.z * w1p[4 * k + 2] + av.w * w1p[4 * k + 3];
            s2 += av.x * w2p[4 * k + 0] + av.y * w2p[4 * k + 1] + av.z * w2p[4 * k + 2] + av.w * w2p[4 * k + 3];
            s3 += av.x * w3p[4 * k + 0] + av.y * w3p[4 * k + 1] + av.z * w3p[4 * k + 2] + av.w * w3p[4 * k + 3];
        }
        b[m] = make_float4(silu_f(s0), silu_f(s1), silu_f(s2), silu_f(s3));
    }
}

__device__ __forceinline__ void mlp_body(
    const float* __restrict__ rb, int e,
    const float* __restrict__ w0T, const float* __restrict__ w1T,
    const float* __restrict__ w2T, float4* a) {
    float rbv[RBD];
    #pragma unroll
    for (int k = 0; k < RBD; k++) rbv[k] = rb[(size_t)e * RBD + k];
    float4 b[16];
    #pragma unroll
    for (int m = 0; m < 16; m++) {
        float s0 = 0.f, s1 = 0.f, s2 = 0.f, s3 = 0.f;
        #pragma unroll
        for (int k = 0; k < RBD; k++) {
            float rv = rbv[k];
            s0 += rv * w0T[(4 * m + 0) * RBD + k];
            s1 += rv * w0T[(4 * m + 1) * RBD + k];
            s2 += rv * w0T[(4 * m + 2) * RBD + k];
            s3 += rv * w0T[(4 * m + 3) * RBD + k];
        }
        a[m] = make_float4(silu_f(s0), silu_f(s1), silu_f(s2), silu_f(s3));
    }
    layer64(a, b, w1T);
    layer64(b, a, w2T);   // a holds h2
}

// ---------------- tier A step 1: MLP -> bf16 h2b[p][64] (permuted) ----------------
__global__ __launch_bounds__(256) void k_h2bf(
    const float* __restrict__ rb, const int* __restrict__ elist,
    const float* __restrict__ w0T, const float* __restrict__ w1T,
    const float* __restrict__ w2T,
    unsigned short* __restrict__ h2b, int E_) {
    int p = blockIdx.x * blockDim.x + threadIdx.x;
    if (p >= E_) return;
    int e = elist[p];
    float4 a[16];
    mlp_body(rb, e, w0T, w1T, w2T, a);
    unsigned short* out = h2b + (size_t)p * 64;
    #pragma unroll
    for (int q = 0; q < 16; q += 2) {
        uint4 pk;
        pk.x = (unsigned)f2bf(a[q].x)     | ((unsigned)f2bf(a[q].y) << 16);
        pk.y = (unsigned)f2bf(a[q].z)     | ((unsigned)f2bf(a[q].w) << 16);
        pk.z = (unsigned)f2bf(a[q + 1].x) | ((unsigned)f2bf(a[q + 1].y) << 16);
        pk.w = (unsigned)f2bf(a[q + 1].z) | ((unsigned)f2bf(a[q + 1].w) << 16);
        *(uint4*)(out + q * 4) = pk;
    }
}

// ---------------- tier A step 2: MFMA GEMM -> channel-major Wp[ch][j] ----------------
__global__ __launch_bounds__(256) void k_w3gemm(
    const unsigned short* __restrict__ h2b,
    const unsigned short* __restrict__ w3bs,
    unsigned short* __restrict__ Wp, int E_) {
    const int lane = threadIdx.x & 63;
    const int wv = threadIdx.x >> 6;
    const int rb = blockIdx.x * 4 + wv;
    if (rb * 16 >= E_) return;

    const unsigned short* abase =
        h2b + (((size_t)rb * 16 + (lane & 15)) * 64 + 8 * (lane >> 4));
    short8v a0 = *(const short8v*)abase;
    short8v a1 = *(const short8v*)(abase + 32);

    f32x4 acc[32];
    #pragma unroll
    for (int t = 0; t < 32; t++) acc[t] = (f32x4){0.f, 0.f, 0.f, 0.f};

    const unsigned short* bbase = w3bs + (size_t)lane * 8;
    #pragma unroll
    for (int t = 0; t < 32; t++) {
        short8v b0 = *(const short8v*)(bbase + (size_t)(t * 2 + 0) * 512);
        short8v b1 = *(const short8v*)(bbase + (size_t)(t * 2 + 1) * 512);
        acc[t] = __builtin_amdgcn_mfma_f32_16x16x32_bf16(a0, b0, acc[t], 0, 0, 0);
        acc[t] = __builtin_amdgcn_mfma_f32_16x16x32_bf16(a1, b1, acc[t], 0, 0, 0);
    }

    const int colbase = lane & 15;
    const int rowq = (lane >> 4) * 4;
    const int jbase = rb * 16 + rowq;
    #pragma unroll
    for (int t = 0; t < 32; t++) {
        ushort4 pk = make_ushort4(f2bf(acc[t][0]), f2bf(acc[t][1]),
                                  f2bf(acc[t][2]), f2bf(acc[t][3]));
        *(ushort4*)(Wp + (size_t)(t * 16 + colbase) * E_ + jbase) = pk;
    }
}

// ---------------- tier A step 3: gather, 4 receivers/block + XCD swizzle ----------------
// Each block walks a CONTIGUOUS j-range covering 4 consecutive receivers
// (~128 edges): per channel stream that's ~256B sequential, so fetch sectors
// are fully consumed (1 node/block only used 64B/sector -> ~4-7x overfetch).
// Node-boundary flushes are block-uniform (off[] is the same for all threads).
__global__ __launch_bounds__(256) void k_gather_cm(
    const int* __restrict__ off, const float4* __restrict__ up,
    const int* __restrict__ sp,
    const unsigned short* __restrict__ Wp, int E_,
    const float* __restrict__ y0, const float* __restrict__ y1, int NP,
    float* __restrict__ agg_s, float* __restrict__ agg_v) {
    int blk = blockIdx.x;
    if ((gridDim.x & 7) == 0) {
        blk = (blockIdx.x & 7) * (gridDim.x >> 3) + (blockIdx.x >> 3);
    }
    const int r0 = blk * 4;
    const int tid = threadIdx.x;
    const int half = tid >> 7;
    const int c = tid & 127;

    const unsigned short* __restrict__ wA = Wp + (size_t)tid * E_;
    const unsigned short* __restrict__ wB = Wp + (size_t)(tid + 256) * E_;

    const int jstart = off[r0];
    const int jend = off[r0 + 4];
    int rcur = r0;
    int ecur = off[r0 + 1];

    float accs = 0.f, av0 = 0.f, av1 = 0.f, av2 = 0.f;
    const float SQ3 = 1.7320508075688772f;

    for (int j4 = jstart & ~3; j4 < jend; j4 += 4) {
        ushort4 a4 = *(const ushort4*)(wA + j4);
        ushort4 b4 = *(const ushort4*)(wB + j4);
        int4 s4 = *(const int4*)(sp + j4);
        const unsigned short* ap = (const unsigned short*)&a4;
        const unsigned short* bp = (const unsigned short*)&b4;
        const int* spp = (const int*)&s4;
        #pragma unroll
        for (int q = 0; q < 4; q++) {
            int j = j4 + q;
            if (j < jstart || j >= jend) continue;
            // block-uniform node-boundary flush
            while (j >= ecur) {
                const int co = half * 128 + c;
                agg_s[(size_t)rcur * 256 + co] = accs;
                float* o = agg_v + ((size_t)rcur * 256 + co) * 3;
                o[0] = av0; o[1] = av1; o[2] = av2;
                accs = 0.f; av0 = 0.f; av1 = 0.f; av2 = 0.f;
                rcur++;
                ecur = off[rcur + 1];
            }
            float4 u = up[j];
            int s = spp[q];
            float wa = bf2f(ap[q]);
            float wb = bf2f(bp[q]);
            if (half == 0) {
                float f = y0[(size_t)s * CC + c];
                accs += f * wa;
                float bb = f * wb * SQ3;
                av0 += bb * u.x; av1 += bb * u.y; av2 += bb * u.z;
            } else {
                float f0 = y1[0 * NP + s * CC + c];
                float f1 = y1[1 * NP + s * CC + c];
                float f2 = y1[2 * NP + s * CC + c];
                accs += (f0 * u.x + f1 * u.y + f2 * u.z) * wa;
                av0 += f0 * wb; av1 += f1 * wb; av2 += f2 * wb;
            }
        }
    }
    // flush remaining nodes (incl. trailing zero-degree)
    for (; rcur < r0 + 4; rcur++) {
        const int co = half * 128 + c;
        agg_s[(size_t)rcur * 256 + co] = accs;
        float* o = agg_v + ((size_t)rcur * 256 + co) * 3;
        o[0] = av0; o[1] = av1; o[2] = av2;
        accs = 0.f; av0 = 0.f; av1 = 0.f; av2 = 0.f;
    }
}

// ---------------- tier B: VALU writer (grouped layout) + its gather ----------------
__global__ __launch_bounds__(256) void k_mlp_wp(
    const float* __restrict__ rb, const int* __restrict__ elist,
    const float* __restrict__ w0T, const float* __restrict__ w1T,
    const float* __restrict__ w2T, const float* __restrict__ w3T,
    unsigned short* __restrict__ Wp, int E_) {
    int p = blockIdx.x * blockDim.x + threadIdx.x;
    if (p >= E_) return;
    int e = elist[p];
    const int c0 = blockIdx.y * 128;

    float4 a[16];
    mlp_body(rb, e, w0T, w1T, w2T, a);

    const size_t E4 = (size_t)E_ * 4;
    for (int c = c0; c < c0 + 128; c += 8) {
        float s[8];
        #pragma unroll
        for (int q = 0; q < 8; q++) {
            const float* rp = w3T + (size_t)(c + q) * 64;
            float t0 = 0.f, t1 = 0.f, t2 = 0.f, t3 = 0.f;
            #pragma unroll
            for (int k = 0; k < 16; k++) {
                float4 h = a[k];
                t0 += h.x * rp[4 * k + 0];
                t1 += h.y * rp[4 * k + 1];
                t2 += h.z * rp[4 * k + 2];
                t3 += h.w * rp[4 * k + 3];
            }
            s[q] = (t0 + t1) + (t2 + t3);
        }
        ushort4 pk0 = make_ushort4(f2bf(s[0]), f2bf(s[1]), f2bf(s[2]), f2bf(s[3]));
        ushort4 pk1 = make_ushort4(f2bf(s[4]), f2bf(s[5]), f2bf(s[6]), f2bf(s[7]));
        *(ushort4*)(Wp + (size_t)(c >> 2) * E4 + (size_t)p * 4) = pk0;
        *(ushort4*)(Wp + (size_t)((c >> 2) + 1) * E4 + (size_t)p * 4) = pk1;
    }
}

__global__ __launch_bounds__(512, 2) void k_gather_wg(
    const int* __restrict__ off, const int* __restrict__ elist,
    const int* __restrict__ snd, const float* __restrict__ evec,
    const unsigned short* __restrict__ Wp, int E_,
    const float* __restrict__ y0, const float* __restrict__ y1, int NP,
    float* __restrict__ agg_s, float* __restrict__ agg_v) {
    const int r = blockIdx.x;
    const int tid = threadIdx.x;
    const int part = tid >> 7;
    const int c = tid & 127;

    const int start = off[r];
    const int end = off[r + 1];

    const unsigned short* __restrict__ wstream =
        Wp + (size_t)(tid >> 2) * ((size_t)E_ * 4) + (tid & 3);

    float acc0 = 0.f, acc1 = 0.f, acc2 = 0.f;
    const float SQ3 = 1.7320508075688772f;

    #pragma unroll 2
    for (int j = start; j < end; j++) {
        int e = elist[j];
        e = __builtin_amdgcn_readfirstlane(e);
        int s = snd[e];
        s = __builtin_amdgcn_readfirstlane(s);

        float e0 = evec[(size_t)e * 3 + 0];
        float e1 = evec[(size_t)e * 3 + 1];
        float e2 = evec[(size_t)e * 3 + 2];
        float rn = sqrtf(e0 * e0 + e1 * e1 + e2 * e2);
        float inv = 1.0f / fmaxf(rn, 1e-12f);
        float ux = e0 * inv, uy = e1 * inv, uz = e2 * inv;

        float w = bf2f(wstream[(size_t)j * 4]);

        if (part == 0) {
            acc0 += y0[(size_t)s * CC + c] * w;
        } else if (part == 1) {
            float f = y1[0 * NP + s * CC + c] * ux
                    + y1[1 * NP + s * CC + c] * uy
                    + y1[2 * NP + s * CC + c] * uz;
            acc0 += f * w;
        } else if (part == 2) {
            float bb = y0[(size_t)s * CC + c] * w * SQ3;
            acc0 += bb * ux; acc1 += bb * uy; acc2 += bb * uz;
        } else {
            acc0 += y1[0 * NP + s * CC + c] * w;
            acc1 += y1[1 * NP + s * CC + c] * w;
            acc2 += y1[2 * NP + s * CC + c] * w;
        }
    }

    if (part == 0) {
        agg_s[(size_t)r * 2 * CC + c] = acc0;
    } else if (part == 1) {
        agg_s[(size_t)r * 2 * CC + CC + c] = acc0;
    } else if (part == 2) {
        float* o = agg_v + ((size_t)r * 2 * CC + c) * 3;
        o[0] = acc0; o[1] = acc1; o[2] = acc2;
    } else {
        float* o = agg_v + ((size_t)r * 2 * CC + CC + c) * 3;
        o[0] = acc0; o[1] = acc1; o[2] = acc2;
    }
}

// ---------------- tier C: f32 h2 fallback ----------------
__global__ void k_mlp(const float* __restrict__ rb,
                      const float* __restrict__ w0T, const float* __restrict__ w1T,
                      const float* __restrict__ w2T,
                      float* __restrict__ h2, int E_) {
    int e = blockIdx.x * blockDim.x + threadIdx.x;
    if (e >= E_) return;
    float4 a[16];
    mlp_body(rb, e, w0T, w1T, w2T, a);
    float4* out = (float4*)(h2 + (size_t)e * HH);
    #pragma unroll
    for (int q = 0; q < 16; q++) out[q] = a[q];
}

__global__ __launch_bounds__(512, 1) void k_gather_h2(
    const int* __restrict__ off, const int* __restrict__ elist,
    const int* __restrict__ snd, const float* __restrict__ evec,
    const float* __restrict__ h2, const float* __restrict__ w3T,
    const float* __restrict__ y0, const float* __restrict__ y1, int NP,
    float* __restrict__ agg_s, float* __restrict__ agg_v) {
    const int r = blockIdx.x;
    const int tid = threadIdx.x;
    const int part = tid >> 7;
    const int c = tid & 127;

    const float4* wp = (const float4*)(w3T + (size_t)tid * 64);
    const int start = off[r];
    const int end = off[r + 1];

    float acc0 = 0.f, acc1 = 0.f, acc2 = 0.f;
    const float SQ3 = 1.7320508075688772f;

    for (int j = start; j < end; j++) {
        int e = elist[j];
        e = __builtin_amdgcn_readfirstlane(e);
        int s = snd[e];
        s = __builtin_amdgcn_readfirstlane(s);

        float e0 = evec[(size_t)e * 3 + 0];
        float e1 = evec[(size_t)e * 3 + 1];
        float e2 = evec[(size_t)e * 3 + 2];
        float rn = sqrtf(e0 * e0 + e1 * e1 + e2 * e2);
        float inv = 1.0f / fmaxf(rn, 1e-12f);
        float ux = e0 * inv, uy = e1 * inv, uz = e2 * inv;

        const float4* __restrict__ hp = (const float4*)(h2 + ((size_t)e << 6));
        float ws0 = 0.f, ws1 = 0.f, ws2 = 0.f, ws3 = 0.f;
        #pragma unroll
        for (int k = 0; k < 16; k++) {
            float4 h = hp[k];
            float4 wv = wp[k];
            ws0 += h.x * wv.x; ws1 += h.y * wv.y; ws2 += h.z * wv.z; ws3 += h.w * wv.w;
        }
        float w = (ws0 + ws1) + (ws2 + ws3);

        if (part == 0) {
            acc0 += y0[(size_t)s * CC + c] * w;
        } else if (part == 1) {
            float f = y1[0 * NP + s * CC + c] * ux
                    + y1[1 * NP + s * CC + c] * uy
                    + y1[2 * NP + s * CC + c] * uz;
            acc0 += f * w;
        } else if (part == 2) {
            float bb = y0[(size_t)s * CC + c] * w * SQ3;
            acc0 += bb * ux; acc1 += bb * uy; acc2 += bb * uz;
        } else {
            acc0 += y1[0 * NP + s * CC + c] * w;
            acc1 += y1[1 * NP + s * CC + c] * w;
            acc2 += y1[2 * NP + s * CC + c] * w;
        }
    }

    if (part == 0) {
        agg_s[(size_t)r * 2 * CC + c] = acc0;
    } else if (part == 1) {
        agg_s[(size_t)r * 2 * CC + CC + c] = acc0;
    } else if (part == 2) {
        float* o = agg_v + ((size_t)r * 2 * CC + c) * 3;
        o[0] = acc0; o[1] = acc1; o[2] = acc2;
    } else {
        float* o = agg_v + ((size_t)r * 2 * CC + CC + c) * 3;
        o[0] = acc0; o[1] = acc1; o[2] = acc2;
    }
}

// ---------------- node output ----------------
__global__ __launch_bounds__(256) void k_node_out(
    const float* __restrict__ agg_s, const float* __restrict__ agg_v,
    const float* __restrict__ xs, const float* __restrict__ xv,
    const float* __restrict__ W20, const float* __restrict__ W21,
    const float* __restrict__ Wsk0, const float* __restrict__ Wsk1,
    const int* __restrict__ species,
    float* __restrict__ out, int N) {
    const int tid = threadIdx.x;
    const int n0 = blockIdx.x * 4;

    __shared__ float as_l[4 * 256];
    __shared__ float av_l[4 * 768];
    __shared__ float xs_l[4 * 128];
    __shared__ float xv_l[4 * 384];
    __shared__ float s_l[4 * 256];

    for (int i = tid; i < 4 * 256; i += 256) as_l[i] = agg_s[(size_t)n0 * 256 + i];
    for (int i = tid; i < 4 * 768; i += 256) av_l[i] = agg_v[(size_t)n0 * 768 + i];
    for (int i = tid; i < 4 * 128; i += 256) xs_l[i] = xs[(size_t)n0 * 128 + i];
    for (int i = tid; i < 4 * 384; i += 256) xv_l[i] = xv[(size_t)n0 * 384 + i];
    int sp[4];
    #pragma unroll
    for (int n = 0; n < 4; n++) sp[n] = species[n0 + n];
    __syncthreads();

    const float k_mat = 0.17677669529663687f * 0.0625f; // inv_nb * inv_2c
    const float inv_c = 0.08838834764831845f;

    {
        const int d = tid;
        float am[4] = {0.f, 0.f, 0.f, 0.f};
        for (int cc = 0; cc < 256; cc++) {
            float w = W20[cc * 256 + d];
            #pragma unroll
            for (int n = 0; n < 4; n++) am[n] += as_l[n * 256 + cc] * w;
        }
        float ak[4] = {0.f, 0.f, 0.f, 0.f};
        for (int cc = 0; cc < 128; cc++) {
            #pragma unroll
            for (int n = 0; n < 4; n++) {
                float w = Wsk0[((size_t)sp[n] * 128 + cc) * 256 + d];
                ak[n] += xs_l[n * 128 + cc] * w;
            }
        }
        #pragma unroll
        for (int n = 0; n < 4; n++) s_l[n * 256 + d] = am[n] * k_mat + ak[n] * inv_c;
    }
    __syncthreads();

    if (tid < 128) {
        #pragma unroll
        for (int n = 0; n < 4; n++)
            out[(size_t)(n0 + n) * 512 + tid] = silu_f(s_l[n * 256 + tid]);
    }

    {
        const int d = tid & 127;
        const int half = tid >> 7;
        int spB[2];
        #pragma unroll
        for (int nn = 0; nn < 2; nn++) spB[nn] = species[n0 + half * 2 + nn];

        float am[2][3] = {};
        for (int cc = 0; cc < 256; cc++) {
            float w = W21[cc * 128 + d];
            #pragma unroll
            for (int nn = 0; nn < 2; nn++) {
                int n = half * 2 + nn;
                #pragma unroll
                for (int i = 0; i < 3; i++) am[nn][i] += av_l[n * 768 + cc * 3 + i] * w;
            }
        }
        float ak[2][3] = {};
        for (int cc = 0; cc < 128; cc++) {
            #pragma unroll
            for (int nn = 0; nn < 2; nn++) {
                int n = half * 2 + nn;
                float w = Wsk1[((size_t)spB[nn] * 128 + cc) * 128 + d];
                #pragma unroll
                for (int i = 0; i < 3; i++) ak[nn][i] += xv_l[n * 384 + cc * 3 + i] * w;
            }
        }
        #pragma unroll
        for (int nn = 0; nn < 2; nn++) {
            int n = half * 2 + nn;
            float g = silu_f(s_l[n * 256 + 128 + d]);
            #pragma unroll
            for (int i = 0; i < 3; i++)
                out[(size_t)(n0 + n) * 512 + 128 + d * 3 + i] =
                    (am[nn][i] * k_mat + ak[nn][i] * inv_c) * g;
        }
    }
}

extern "C" void kernel_launch(void* const* d_in, const int* in_sizes, int n_in,
                              void* d_out, int out_size, void* d_ws, size_t ws_size,
                              hipStream_t stream) {
    const float* xs   = (const float*)d_in[0];
    const float* xv   = (const float*)d_in[1];
    const float* evec = (const float*)d_in[2];
    const float* rb   = (const float*)d_in[3];
    const float* W10  = (const float*)d_in[4];
    const float* W11  = (const float*)d_in[5];
    const float* w0   = (const float*)d_in[6];
    const float* w1   = (const float*)d_in[7];
    const float* w2   = (const float*)d_in[8];
    const float* w3   = (const float*)d_in[9];
    const float* W20  = (const float*)d_in[10];
    const float* W21  = (const float*)d_in[11];
    const float* Wsk0 = (const float*)d_in[12];
    const float* Wsk1 = (const float*)d_in[13];
    const int* species = (const int*)d_in[14];
    const int* snd = (const int*)d_in[15];
    const int* rcv = (const int*)d_in[16];

    const int N = in_sizes[0] / CC;   // 4000
    const int E = in_sizes[2] / 3;    // 128000
    const int NP = N * CC;

    float* ws   = (float*)d_ws;
    float* y0   = ws;
    float* y1   = y0 + (size_t)N * CC;
    float* aggs = y1 + (size_t)N * CC * 3;
    float* aggv = aggs + (size_t)N * 2 * CC;
    float* w0T  = aggv + (size_t)N * 2 * CC * 3;
    float* w1T  = w0T + 64 * 8;
    float* w2T  = w1T + 64 * 64;
    float* w3T  = w2T + 64 * 64;
    unsigned short* w3bs = (unsigned short*)(w3T + 512 * 64);   // 32768 bf16
    int*   deg  = (int*)(w3bs + 32768);
    int*   cur  = deg + 4096;
    int*   off  = cur + 4096;
    int*   elist = off + 4160;
    float4* up  = (float4*)(elist + E);      // E float4 (16B-aligned)
    int*   sp   = (int*)(up + E);            // E ints
    void*  big  = (void*)(sp + E);

    size_t base_bytes = (size_t)((char*)big - (char*)d_ws);
    size_t wp_bytes   = (size_t)E * WDIM * sizeof(unsigned short);
    size_t need_A = base_bytes + wp_bytes + (size_t)E * 64 * sizeof(unsigned short);
    size_t need_B = base_bytes + wp_bytes;

    unsigned short* Wp  = (unsigned short*)big;
    unsigned short* h2b = Wp + (size_t)E * WDIM;

    hipMemsetAsync(deg, 0, 2 * 4096 * sizeof(int), stream);
    hipLaunchKernelGGL(k_hist, dim3((E + 255) / 256), dim3(256), 0, stream, rcv, deg, E);
    hipLaunchKernelGGL(k_scan, dim3(1), dim3(1024), 0, stream, deg, off, N);
    hipLaunchKernelGGL(k_scatter, dim3((E + 255) / 256), dim3(256), 0, stream,
                       rcv, off, cur, elist, E);
    hipLaunchKernelGGL(k_prep, dim3(128), dim3(256), 0, stream,
                       w0, w1, w2, w3, w0T, w1T, w2T, w3T, w3bs);
    hipLaunchKernelGGL(k_node_lin, dim3(N / 4), dim3(128), 0, stream,
                       xs, xv, W10, W11, y0, y1, N);

    if (ws_size >= need_A && (E % 64) == 0 && (N % 4) == 0) {
        hipLaunchKernelGGL(k_emeta, dim3((E + 255) / 256), dim3(256), 0, stream,
                           elist, snd, evec, up, sp, E);
        hipLaunchKernelGGL(k_h2bf, dim3((E + 255) / 256), dim3(256), 0, stream,
                           rb, elist, w0T, w1T, w2T, h2b, E);
        hipLaunchKernelGGL(k_w3gemm, dim3(E / 64), dim3(256), 0, stream,
                           h2b, w3bs, Wp, E);
        hipLaunchKernelGGL(k_gather_cm, dim3(N / 4), dim3(256), 0, stream,
                           off, up, sp, Wp, E, y0, y1, NP, aggs, aggv);
    } else if (ws_size >= need_B) {
        hipLaunchKernelGGL(k_mlp_wp, dim3((E + 255) / 256, 4), dim3(256), 0, stream,
                           rb, elist, w0T, w1T, w2T, w3T, Wp, E);
        hipLaunchKernelGGL(k_gather_wg, dim3(N), dim3(512), 0, stream,
                           off, elist, snd, evec, Wp, E, y0, y1, NP, aggs, aggv);
    } else {
        hipLaunchKernelGGL(k_mlp, dim3((E + 255) / 256), dim3(256), 0, stream,
                           rb, w0T, w1T, w2T, (float*)big, E);
        hipLaunchKernelGGL(k_gather_h2, dim3(N), dim3(512), 0, stream,
                           off, elist, snd, evec, (const float*)big, w3T,
                           y0, y1, NP, aggs, aggv);
    }

    hipLaunchKernelGGL(k_node_out, dim3(N / 4), dim3(256), 0, stream,
                       aggs, aggv, xs, xv, W20, W21, Wsk0, Wsk1, species,
                       (float*)d_out, N);
}

// Round 12
// 348.118 us; speedup vs baseline: 1.8341x; 1.8341x over previous
//
#include <hip/hip_runtime.h>
#include <math.h>

#define CC 128
#define HH 64
#define RBD 8
#define WDIM 512

typedef __attribute__((ext_vector_type(8))) short short8v;
typedef __attribute__((ext_vector_type(4))) float f32x4;

__device__ __forceinline__ float silu_f(float x) {
    return x / (1.0f + __expf(-x));
}

__device__ __forceinline__ unsigned short f2bf(float x) {
    unsigned int b = __float_as_uint(x);
    unsigned int r = (b + 0x7FFFu + ((b >> 16) & 1u)) >> 16;
    return (unsigned short)r;
}

__device__ __forceinline__ float bf2f(unsigned short u) {
    return __uint_as_float(((unsigned int)u) << 16);
}

// ---------------- transpose MLP weights + build MFMA B-fragments ----------------
__global__ void k_prep(const float* __restrict__ w0, const float* __restrict__ w1,
                       const float* __restrict__ w2, const float* __restrict__ w3,
                       float* __restrict__ w0T, float* __restrict__ w1T,
                       float* __restrict__ w2T, float* __restrict__ w3T,
                       unsigned short* __restrict__ w3bs) {
    int i = blockIdx.x * blockDim.x + threadIdx.x;
    if (i < 64 * 8) { int m = i / 8, k = i % 8; w0T[i] = w0[k * 64 + m]; }
    if (i < 64 * 64) { int m = i / 64, k = i % 64; w1T[i] = w1[k * 64 + m]; w2T[i] = w2[k * 64 + m]; }
    if (i < 512 * 64) { int j = i / 64, k = i % 64; w3T[i] = w3[k * 512 + j]; }
    if (i < 32768) {
        int t = i >> 10, ch = (i >> 9) & 1, lane = (i >> 3) & 63, j = i & 7;
        int k = ch * 32 + 8 * (lane >> 4) + j;
        int n = t * 16 + (lane & 15);
        w3bs[i] = f2bf(w3[k * 512 + n]);
    }
}

// ---------------- CSR build ----------------
__global__ void k_hist(const int* __restrict__ rcv, int* __restrict__ deg, int E_) {
    int e = blockIdx.x * blockDim.x + threadIdx.x;
    if (e < E_) atomicAdd(&deg[rcv[e]], 1);
}

__global__ __launch_bounds__(1024) void k_scan(const int* __restrict__ deg,
                                               int* __restrict__ off, int N) {
    __shared__ int s[1024];
    int t = threadIdx.x;
    int b = t * 4;
    int a0 = (b + 0 < N) ? deg[b + 0] : 0;
    int a1 = (b + 1 < N) ? deg[b + 1] : 0;
    int a2 = (b + 2 < N) ? deg[b + 2] : 0;
    int a3 = (b + 3 < N) ? deg[b + 3] : 0;
    int part = a0 + a1 + a2 + a3;
    s[t] = part;
    __syncthreads();
    for (int d = 1; d < 1024; d <<= 1) {
        int v = (t >= d) ? s[t - d] : 0;
        __syncthreads();
        s[t] += v;
        __syncthreads();
    }
    int excl = s[t] - part;
    if (b + 0 <= N) off[b + 0] = excl;
    if (b + 1 <= N) off[b + 1] = excl + a0;
    if (b + 2 <= N) off[b + 2] = excl + a0 + a1;
    if (b + 3 <= N) off[b + 3] = excl + a0 + a1 + a2;
}

__global__ void k_scatter(const int* __restrict__ rcv, const int* __restrict__ off,
                          int* __restrict__ cur, int* __restrict__ elist, int E_) {
    int e = blockIdx.x * blockDim.x + threadIdx.x;
    if (e < E_) {
        int r = rcv[e];
        int p = atomicAdd(&cur[r], 1);
        elist[off[r] + p] = e;
    }
}

// ---------------- edge meta: permuted unit vectors + senders ----------------
__global__ void k_emeta(const int* __restrict__ elist, const int* __restrict__ snd,
                        const float* __restrict__ evec,
                        float4* __restrict__ up, int* __restrict__ sp, int E_) {
    int p = blockIdx.x * blockDim.x + threadIdx.x;
    if (p >= E_) return;
    int e = elist[p];
    float e0 = evec[(size_t)e * 3 + 0];
    float e1 = evec[(size_t)e * 3 + 1];
    float e2 = evec[(size_t)e * 3 + 2];
    float rn = sqrtf(e0 * e0 + e1 * e1 + e2 * e2);
    float inv = 1.0f / fmaxf(rn, 1e-12f);
    up[p] = make_float4(e0 * inv, e1 * inv, e2 * inv, 0.f);
    sp[p] = snd[e];
}

// ---------------- node linear (planar y1: [3][N][C]) ----------------
__global__ __launch_bounds__(128) void k_node_lin(
    const float* __restrict__ xs, const float* __restrict__ xv,
    const float* __restrict__ W10, const float* __restrict__ W11,
    float* __restrict__ y0, float* __restrict__ y1, int N) {
    const int d = threadIdx.x;
    const int n0 = blockIdx.x * 4;
    const int NP = N * CC;
    const float inv_c = 0.08838834764831845f;
    float a0[4] = {0.f, 0.f, 0.f, 0.f};
    float av[4][3] = {};
    #pragma unroll 4
    for (int c = 0; c < CC; c++) {
        float w10 = W10[c * CC + d];
        float w11 = W11[c * CC + d];
        #pragma unroll
        for (int n = 0; n < 4; n++) {
            a0[n] += xs[(n0 + n) * CC + c] * w10;
            #pragma unroll
            for (int i = 0; i < 3; i++)
                av[n][i] += xv[((n0 + n) * CC + c) * 3 + i] * w11;
        }
    }
    #pragma unroll
    for (int n = 0; n < 4; n++) {
        y0[(n0 + n) * CC + d] = a0[n] * inv_c;
        #pragma unroll
        for (int i = 0; i < 3; i++)
            y1[i * NP + (n0 + n) * CC + d] = av[n][i] * inv_c;
    }
}

// ---------------- shared MLP body: h2 into a[16] ----------------
__device__ __forceinline__ void layer64(const float4* a, float4* b,
                                        const float* __restrict__ W) {
    #pragma unroll
    for (int m = 0; m < 16; m++) {
        float s0 = 0.f, s1 = 0.f, s2 = 0.f, s3 = 0.f;
        const float* w0p = W + (4 * m + 0) * 64;
        const float* w1p = W + (4 * m + 1) * 64;
        const float* w2p = W + (4 * m + 2) * 64;
        const float* w3p = W + (4 * m + 3) * 64;
        #pragma unroll
        for (int k = 0; k < 16; k++) {
            float4 av = a[k];
            s0 += av.x * w0p[4 * k + 0] + av.y * w0p[4 * k + 1] + av.z * w0p[4 * k + 2] + av.w * w0p[4 * k + 3];
            s1 += av.x * w1p[4 * k + 0] + av.y * w1p[4 * k + 1] + av.z * w1p[4 * k + 2] + av.w * w1p[4 * k + 3];
            s2 += av.x * w2p[4 * k + 0] + av.y * w2p[4 * k + 1] + av.z * w2p[4 * k + 2] + av.w * w2p[4 * k + 3];
            s3 += av.x * w3p[4 * k + 0] + av.y * w3p[4 * k + 1] + av.z * w3p[4 * k + 2] + av.w * w3p[4 * k + 3];
        }
        b[m] = make_float4(silu_f(s0), silu_f(s1), silu_f(s2), silu_f(s3));
    }
}

__device__ __forceinline__ void mlp_body(
    const float* __restrict__ rb, int e,
    const float* __restrict__ w0T, const float* __restrict__ w1T,
    const float* __restrict__ w2T, float4* a) {
    float rbv[RBD];
    #pragma unroll
    for (int k = 0; k < RBD; k++) rbv[k] = rb[(size_t)e * RBD + k];
    float4 b[16];
    #pragma unroll
    for (int m = 0; m < 16; m++) {
        float s0 = 0.f, s1 = 0.f, s2 = 0.f, s3 = 0.f;
        #pragma unroll
        for (int k = 0; k < RBD; k++) {
            float rv = rbv[k];
            s0 += rv * w0T[(4 * m + 0) * RBD + k];
            s1 += rv * w0T[(4 * m + 1) * RBD + k];
            s2 += rv * w0T[(4 * m + 2) * RBD + k];
            s3 += rv * w0T[(4 * m + 3) * RBD + k];
        }
        a[m] = make_float4(silu_f(s0), silu_f(s1), silu_f(s2), silu_f(s3));
    }
    layer64(a, b, w1T);
    layer64(b, a, w2T);   // a holds h2
}

// ---------------- tier A step 1: MLP -> bf16 h2b[p][64] (permuted) ----------------
__global__ __launch_bounds__(256) void k_h2bf(
    const float* __restrict__ rb, const int* __restrict__ elist,
    const float* __restrict__ w0T, const float* __restrict__ w1T,
    const float* __restrict__ w2T,
    unsigned short* __restrict__ h2b, int E_) {
    int p = blockIdx.x * blockDim.x + threadIdx.x;
    if (p >= E_) return;
    int e = elist[p];
    float4 a[16];
    mlp_body(rb, e, w0T, w1T, w2T, a);
    unsigned short* out = h2b + (size_t)p * 64;
    #pragma unroll
    for (int q = 0; q < 16; q += 2) {
        uint4 pk;
        pk.x = (unsigned)f2bf(a[q].x)     | ((unsigned)f2bf(a[q].y) << 16);
        pk.y = (unsigned)f2bf(a[q].z)     | ((unsigned)f2bf(a[q].w) << 16);
        pk.z = (unsigned)f2bf(a[q + 1].x) | ((unsigned)f2bf(a[q + 1].y) << 16);
        pk.w = (unsigned)f2bf(a[q + 1].z) | ((unsigned)f2bf(a[q + 1].w) << 16);
        *(uint4*)(out + q * 4) = pk;
    }
}

// ---------------- tier A step 2: MFMA GEMM -> pair-packed edge-major Wq ----------------
// Wq[j][k] (uint, 256/row) packs channels (k, k+256) as 2xbf16. Row = 1KB,
// read by gather fully-coalesced and consumed immediately (no line revisits).
// acc[t] holds ch t*16+col; pair t with t+16. Stores: 16 lanes x 4B = 64B
// full segments; each row completed within the wave.
__global__ __launch_bounds__(256) void k_w3gemm(
    const unsigned short* __restrict__ h2b,
    const unsigned short* __restrict__ w3bs,
    unsigned int* __restrict__ Wq, int E_) {
    const int lane = threadIdx.x & 63;
    const int wv = threadIdx.x >> 6;
    const int rb = blockIdx.x * 4 + wv;
    if (rb * 16 >= E_) return;

    const unsigned short* abase =
        h2b + (((size_t)rb * 16 + (lane & 15)) * 64 + 8 * (lane >> 4));
    short8v a0 = *(const short8v*)abase;
    short8v a1 = *(const short8v*)(abase + 32);

    f32x4 acc[32];
    #pragma unroll
    for (int t = 0; t < 32; t++) acc[t] = (f32x4){0.f, 0.f, 0.f, 0.f};

    const unsigned short* bbase = w3bs + (size_t)lane * 8;
    #pragma unroll
    for (int t = 0; t < 32; t++) {
        short8v b0 = *(const short8v*)(bbase + (size_t)(t * 2 + 0) * 512);
        short8v b1 = *(const short8v*)(bbase + (size_t)(t * 2 + 1) * 512);
        acc[t] = __builtin_amdgcn_mfma_f32_16x16x32_bf16(a0, b0, acc[t], 0, 0, 0);
        acc[t] = __builtin_amdgcn_mfma_f32_16x16x32_bf16(a1, b1, acc[t], 0, 0, 0);
    }

    const int colbase = lane & 15;
    const int rowq = (lane >> 4) * 4;
    const int jbase = rb * 16 + rowq;
    #pragma unroll
    for (int t = 0; t < 16; t++) {
        #pragma unroll
        for (int rr = 0; rr < 4; rr++) {
            unsigned lo = f2bf(acc[t][rr]);
            unsigned hi = f2bf(acc[t + 16][rr]);
            Wq[(size_t)(jbase + rr) * 256 + t * 16 + colbase] = lo | (hi << 16);
        }
    }
}

// ---------------- tier A step 3: edge-major gather (merged halves) ----------------
// 256 threads: half=tid>>7, c=tid&127. Thread tid reads Wq[j][tid] =
// (wa=ch tid, wb=ch tid+256) in ONE coalesced dword per edge.
// half0: agg_s[c] (y0*wa) + agg_v[c] (y0*wb*sqrt3*u)  [1 y-load]
// half1: agg_s[C+c] ((y1.u)*wa) + agg_v[C+c] (y1*wb)  [3 y-loads]
__global__ __launch_bounds__(256, 4) void k_gather_em(
    const int* __restrict__ off, const float4* __restrict__ up,
    const int* __restrict__ sp, const unsigned int* __restrict__ Wq,
    const float* __restrict__ y0, const float* __restrict__ y1, int NP,
    float* __restrict__ agg_s, float* __restrict__ agg_v) {
    const int r = blockIdx.x;
    const int tid = threadIdx.x;
    const int half = tid >> 7;
    const int c = tid & 127;
    const int start = off[r];
    const int end = off[r + 1];

    float accs = 0.f, av0 = 0.f, av1 = 0.f, av2 = 0.f;
    const float SQ3 = 1.7320508075688772f;

    #pragma unroll 2
    for (int j = start; j < end; j++) {
        unsigned wq = Wq[(size_t)j * 256 + tid];
        float4 u = up[j];
        int s = __builtin_amdgcn_readfirstlane(sp[j]);
        float wa = bf2f((unsigned short)(wq & 0xFFFFu));
        float wb = bf2f((unsigned short)(wq >> 16));
        if (half == 0) {
            float f = y0[(size_t)s * CC + c];
            accs += f * wa;
            float bb = f * wb * SQ3;
            av0 += bb * u.x; av1 += bb * u.y; av2 += bb * u.z;
        } else {
            float f0 = y1[0 * NP + s * CC + c];
            float f1 = y1[1 * NP + s * CC + c];
            float f2 = y1[2 * NP + s * CC + c];
            accs += (f0 * u.x + f1 * u.y + f2 * u.z) * wa;
            av0 += f0 * wb; av1 += f1 * wb; av2 += f2 * wb;
        }
    }

    agg_s[(size_t)r * 256 + tid] = accs;
    float* o = agg_v + ((size_t)r * 256 + tid) * 3;
    o[0] = av0; o[1] = av1; o[2] = av2;
}

// ---------------- tier B: VALU writer (grouped layout) + its gather ----------------
__global__ __launch_bounds__(256) void k_mlp_wp(
    const float* __restrict__ rb, const int* __restrict__ elist,
    const float* __restrict__ w0T, const float* __restrict__ w1T,
    const float* __restrict__ w2T, const float* __restrict__ w3T,
    unsigned short* __restrict__ Wp, int E_) {
    int p = blockIdx.x * blockDim.x + threadIdx.x;
    if (p >= E_) return;
    int e = elist[p];
    const int c0 = blockIdx.y * 128;

    float4 a[16];
    mlp_body(rb, e, w0T, w1T, w2T, a);

    const size_t E4 = (size_t)E_ * 4;
    for (int c = c0; c < c0 + 128; c += 8) {
        float s[8];
        #pragma unroll
        for (int q = 0; q < 8; q++) {
            const float* rp = w3T + (size_t)(c + q) * 64;
            float t0 = 0.f, t1 = 0.f, t2 = 0.f, t3 = 0.f;
            #pragma unroll
            for (int k = 0; k < 16; k++) {
                float4 h = a[k];
                t0 += h.x * rp[4 * k + 0];
                t1 += h.y * rp[4 * k + 1];
                t2 += h.z * rp[4 * k + 2];
                t3 += h.w * rp[4 * k + 3];
            }
            s[q] = (t0 + t1) + (t2 + t3);
        }
        ushort4 pk0 = make_ushort4(f2bf(s[0]), f2bf(s[1]), f2bf(s[2]), f2bf(s[3]));
        ushort4 pk1 = make_ushort4(f2bf(s[4]), f2bf(s[5]), f2bf(s[6]), f2bf(s[7]));
        *(ushort4*)(Wp + (size_t)(c >> 2) * E4 + (size_t)p * 4) = pk0;
        *(ushort4*)(Wp + (size_t)((c >> 2) + 1) * E4 + (size_t)p * 4) = pk1;
    }
}

__global__ __launch_bounds__(512, 2) void k_gather_wg(
    const int* __restrict__ off, const int* __restrict__ elist,
    const int* __restrict__ snd, const float* __restrict__ evec,
    const unsigned short* __restrict__ Wp, int E_,
    const float* __restrict__ y0, const float* __restrict__ y1, int NP,
    float* __restrict__ agg_s, float* __restrict__ agg_v) {
    const int r = blockIdx.x;
    const int tid = threadIdx.x;
    const int part = tid >> 7;
    const int c = tid & 127;

    const int start = off[r];
    const int end = off[r + 1];

    const unsigned short* __restrict__ wstream =
        Wp + (size_t)(tid >> 2) * ((size_t)E_ * 4) + (tid & 3);

    float acc0 = 0.f, acc1 = 0.f, acc2 = 0.f;
    const float SQ3 = 1.7320508075688772f;

    #pragma unroll 2
    for (int j = start; j < end; j++) {
        int e = elist[j];
        e = __builtin_amdgcn_readfirstlane(e);
        int s = snd[e];
        s = __builtin_amdgcn_readfirstlane(s);

        float e0 = evec[(size_t)e * 3 + 0];
        float e1 = evec[(size_t)e * 3 + 1];
        float e2 = evec[(size_t)e * 3 + 2];
        float rn = sqrtf(e0 * e0 + e1 * e1 + e2 * e2);
        float inv = 1.0f / fmaxf(rn, 1e-12f);
        float ux = e0 * inv, uy = e1 * inv, uz = e2 * inv;

        float w = bf2f(wstream[(size_t)j * 4]);

        if (part == 0) {
            acc0 += y0[(size_t)s * CC + c] * w;
        } else if (part == 1) {
            float f = y1[0 * NP + s * CC + c] * ux
                    + y1[1 * NP + s * CC + c] * uy
                    + y1[2 * NP + s * CC + c] * uz;
            acc0 += f * w;
        } else if (part == 2) {
            float bb = y0[(size_t)s * CC + c] * w * SQ3;
            acc0 += bb * ux; acc1 += bb * uy; acc2 += bb * uz;
        } else {
            acc0 += y1[0 * NP + s * CC + c] * w;
            acc1 += y1[1 * NP + s * CC + c] * w;
            acc2 += y1[2 * NP + s * CC + c] * w;
        }
    }

    if (part == 0) {
        agg_s[(size_t)r * 2 * CC + c] = acc0;
    } else if (part == 1) {
        agg_s[(size_t)r * 2 * CC + CC + c] = acc0;
    } else if (part == 2) {
        float* o = agg_v + ((size_t)r * 2 * CC + c) * 3;
        o[0] = acc0; o[1] = acc1; o[2] = acc2;
    } else {
        float* o = agg_v + ((size_t)r * 2 * CC + CC + c) * 3;
        o[0] = acc0; o[1] = acc1; o[2] = acc2;
    }
}

// ---------------- tier C: f32 h2 fallback ----------------
__global__ void k_mlp(const float* __restrict__ rb,
                      const float* __restrict__ w0T, const float* __restrict__ w1T,
                      const float* __restrict__ w2T,
                      float* __restrict__ h2, int E_) {
    int e = blockIdx.x * blockDim.x + threadIdx.x;
    if (e >= E_) return;
    float4 a[16];
    mlp_body(rb, e, w0T, w1T, w2T, a);
    float4* out = (float4*)(h2 + (size_t)e * HH);
    #pragma unroll
    for (int q = 0; q < 16; q++) out[q] = a[q];
}

__global__ __launch_bounds__(512, 1) void k_gather_h2(
    const int* __restrict__ off, const int* __restrict__ elist,
    const int* __restrict__ snd, const float* __restrict__ evec,
    const float* __restrict__ h2, const float* __restrict__ w3T,
    const float* __restrict__ y0, const float* __restrict__ y1, int NP,
    float* __restrict__ agg_s, float* __restrict__ agg_v) {
    const int r = blockIdx.x;
    const int tid = threadIdx.x;
    const int part = tid >> 7;
    const int c = tid & 127;

    const float4* wp = (const float4*)(w3T + (size_t)tid * 64);
    const int start = off[r];
    const int end = off[r + 1];

    float acc0 = 0.f, acc1 = 0.f, acc2 = 0.f;
    const float SQ3 = 1.7320508075688772f;

    for (int j = start; j < end; j++) {
        int e = elist[j];
        e = __builtin_amdgcn_readfirstlane(e);
        int s = snd[e];
        s = __builtin_amdgcn_readfirstlane(s);

        float e0 = evec[(size_t)e * 3 + 0];
        float e1 = evec[(size_t)e * 3 + 1];
        float e2 = evec[(size_t)e * 3 + 2];
        float rn = sqrtf(e0 * e0 + e1 * e1 + e2 * e2);
        float inv = 1.0f / fmaxf(rn, 1e-12f);
        float ux = e0 * inv, uy = e1 * inv, uz = e2 * inv;

        const float4* __restrict__ hp = (const float4*)(h2 + ((size_t)e << 6));
        float ws0 = 0.f, ws1 = 0.f, ws2 = 0.f, ws3 = 0.f;
        #pragma unroll
        for (int k = 0; k < 16; k++) {
            float4 h = hp[k];
            float4 wv = wp[k];
            ws0 += h.x * wv.x; ws1 += h.y * wv.y; ws2 += h.z * wv.z; ws3 += h.w * wv.w;
        }
        float w = (ws0 + ws1) + (ws2 + ws3);

        if (part == 0) {
            acc0 += y0[(size_t)s * CC + c] * w;
        } else if (part == 1) {
            float f = y1[0 * NP + s * CC + c] * ux
                    + y1[1 * NP + s * CC + c] * uy
                    + y1[2 * NP + s * CC + c] * uz;
            acc0 += f * w;
        } else if (part == 2) {
            float bb = y0[(size_t)s * CC + c] * w * SQ3;
            acc0 += bb * ux; acc1 += bb * uy; acc2 += bb * uz;
        } else {
            acc0 += y1[0 * NP + s * CC + c] * w;
            acc1 += y1[1 * NP + s * CC + c] * w;
            acc2 += y1[2 * NP + s * CC + c] * w;
        }
    }

    if (part == 0) {
        agg_s[(size_t)r * 2 * CC + c] = acc0;
    } else if (part == 1) {
        agg_s[(size_t)r * 2 * CC + CC + c] = acc0;
    } else if (part == 2) {
        float* o = agg_v + ((size_t)r * 2 * CC + c) * 3;
        o[0] = acc0; o[1] = acc1; o[2] = acc2;
    } else {
        float* o = agg_v + ((size_t)r * 2 * CC + CC + c) * 3;
        o[0] = acc0; o[1] = acc1; o[2] = acc2;
    }
}

// ---------------- node output ----------------
__global__ __launch_bounds__(256) void k_node_out(
    const float* __restrict__ agg_s, const float* __restrict__ agg_v,
    const float* __restrict__ xs, const float* __restrict__ xv,
    const float* __restrict__ W20, const float* __restrict__ W21,
    const float* __restrict__ Wsk0, const float* __restrict__ Wsk1,
    const int* __restrict__ species,
    float* __restrict__ out, int N) {
    const int tid = threadIdx.x;
    const int n0 = blockIdx.x * 4;

    __shared__ float as_l[4 * 256];
    __shared__ float av_l[4 * 768];
    __shared__ float xs_l[4 * 128];
    __shared__ float xv_l[4 * 384];
    __shared__ float s_l[4 * 256];

    for (int i = tid; i < 4 * 256; i += 256) as_l[i] = agg_s[(size_t)n0 * 256 + i];
    for (int i = tid; i < 4 * 768; i += 256) av_l[i] = agg_v[(size_t)n0 * 768 + i];
    for (int i = tid; i < 4 * 128; i += 256) xs_l[i] = xs[(size_t)n0 * 128 + i];
    for (int i = tid; i < 4 * 384; i += 256) xv_l[i] = xv[(size_t)n0 * 384 + i];
    int sp[4];
    #pragma unroll
    for (int n = 0; n < 4; n++) sp[n] = species[n0 + n];
    __syncthreads();

    const float k_mat = 0.17677669529663687f * 0.0625f; // inv_nb * inv_2c
    const float inv_c = 0.08838834764831845f;

    {
        const int d = tid;
        float am[4] = {0.f, 0.f, 0.f, 0.f};
        for (int cc = 0; cc < 256; cc++) {
            float w = W20[cc * 256 + d];
            #pragma unroll
            for (int n = 0; n < 4; n++) am[n] += as_l[n * 256 + cc] * w;
        }
        float ak[4] = {0.f, 0.f, 0.f, 0.f};
        for (int cc = 0; cc < 128; cc++) {
            #pragma unroll
            for (int n = 0; n < 4; n++) {
                float w = Wsk0[((size_t)sp[n] * 128 + cc) * 256 + d];
                ak[n] += xs_l[n * 128 + cc] * w;
            }
        }
        #pragma unroll
        for (int n = 0; n < 4; n++) s_l[n * 256 + d] = am[n] * k_mat + ak[n] * inv_c;
    }
    __syncthreads();

    if (tid < 128) {
        #pragma unroll
        for (int n = 0; n < 4; n++)
            out[(size_t)(n0 + n) * 512 + tid] = silu_f(s_l[n * 256 + tid]);
    }

    {
        const int d = tid & 127;
        const int half = tid >> 7;
        int spB[2];
        #pragma unroll
        for (int nn = 0; nn < 2; nn++) spB[nn] = species[n0 + half * 2 + nn];

        float am[2][3] = {};
        for (int cc = 0; cc < 256; cc++) {
            float w = W21[cc * 128 + d];
            #pragma unroll
            for (int nn = 0; nn < 2; nn++) {
                int n = half * 2 + nn;
                #pragma unroll
                for (int i = 0; i < 3; i++) am[nn][i] += av_l[n * 768 + cc * 3 + i] * w;
            }
        }
        float ak[2][3] = {};
        for (int cc = 0; cc < 128; cc++) {
            #pragma unroll
            for (int nn = 0; nn < 2; nn++) {
                int n = half * 2 + nn;
                float w = Wsk1[((size_t)spB[nn] * 128 + cc) * 128 + d];
                #pragma unroll
                for (int i = 0; i < 3; i++) ak[nn][i] += xv_l[n * 384 + cc * 3 + i] * w;
            }
        }
        #pragma unroll
        for (int nn = 0; nn < 2; nn++) {
            int n = half * 2 + nn;
            float g = silu_f(s_l[n * 256 + 128 + d]);
            #pragma unroll
            for (int i = 0; i < 3; i++)
                out[(size_t)(n0 + n) * 512 + 128 + d * 3 + i] =
                    (am[nn][i] * k_mat + ak[nn][i] * inv_c) * g;
        }
    }
}

extern "C" void kernel_launch(void* const* d_in, const int* in_sizes, int n_in,
                              void* d_out, int out_size, void* d_ws, size_t ws_size,
                              hipStream_t stream) {
    const float* xs   = (const float*)d_in[0];
    const float* xv   = (const float*)d_in[1];
    const float* evec = (const float*)d_in[2];
    const float* rb   = (const float*)d_in[3];
    const float* W10  = (const float*)d_in[4];
    const float* W11  = (const float*)d_in[5];
    const float* w0   = (const float*)d_in[6];
    const float* w1   = (const float*)d_in[7];
    const float* w2   = (const float*)d_in[8];
    const float* w3   = (const float*)d_in[9];
    const float* W20  = (const float*)d_in[10];
    const float* W21  = (const float*)d_in[11];
    const float* Wsk0 = (const float*)d_in[12];
    const float* Wsk1 = (const float*)d_in[13];
    const int* species = (const int*)d_in[14];
    const int* snd = (const int*)d_in[15];
    const int* rcv = (const int*)d_in[16];

    const int N = in_sizes[0] / CC;   // 4000
    const int E = in_sizes[2] / 3;    // 128000
    const int NP = N * CC;

    float* ws   = (float*)d_ws;
    float* y0   = ws;
    float* y1   = y0 + (size_t)N * CC;
    float* aggs = y1 + (size_t)N * CC * 3;
    float* aggv = aggs + (size_t)N * 2 * CC;
    float* w0T  = aggv + (size_t)N * 2 * CC * 3;
    float* w1T  = w0T + 64 * 8;
    float* w2T  = w1T + 64 * 64;
    float* w3T  = w2T + 64 * 64;
    unsigned short* w3bs = (unsigned short*)(w3T + 512 * 64);   // 32768 bf16
    int*   deg  = (int*)(w3bs + 32768);
    int*   cur  = deg + 4096;
    int*   off  = cur + 4096;
    int*   elist = off + 4160;
    float4* up  = (float4*)(elist + E);      // E float4 (16B-aligned)
    int*   sp   = (int*)(up + E);            // E ints
    void*  big  = (void*)(sp + E);

    size_t base_bytes = (size_t)((char*)big - (char*)d_ws);
    size_t wp_bytes   = (size_t)E * WDIM * sizeof(unsigned short);
    size_t need_A = base_bytes + wp_bytes + (size_t)E * 64 * sizeof(unsigned short);
    size_t need_B = base_bytes + wp_bytes;

    unsigned int*   Wq  = (unsigned int*)big;                  // E*256 uints
    unsigned short* Wp  = (unsigned short*)big;                // tier B view
    unsigned short* h2b = (unsigned short*)big + (size_t)E * WDIM;

    hipMemsetAsync(deg, 0, 2 * 4096 * sizeof(int), stream);
    hipLaunchKernelGGL(k_hist, dim3((E + 255) / 256), dim3(256), 0, stream, rcv, deg, E);
    hipLaunchKernelGGL(k_scan, dim3(1), dim3(1024), 0, stream, deg, off, N);
    hipLaunchKernelGGL(k_scatter, dim3((E + 255) / 256), dim3(256), 0, stream,
                       rcv, off, cur, elist, E);
    hipLaunchKernelGGL(k_prep, dim3(128), dim3(256), 0, stream,
                       w0, w1, w2, w3, w0T, w1T, w2T, w3T, w3bs);
    hipLaunchKernelGGL(k_node_lin, dim3(N / 4), dim3(128), 0, stream,
                       xs, xv, W10, W11, y0, y1, N);

    if (ws_size >= need_A && (E % 64) == 0) {
        hipLaunchKernelGGL(k_emeta, dim3((E + 255) / 256), dim3(256), 0, stream,
                           elist, snd, evec, up, sp, E);
        hipLaunchKernelGGL(k_h2bf, dim3((E + 255) / 256), dim3(256), 0, stream,
                           rb, elist, w0T, w1T, w2T, h2b, E);
        hipLaunchKernelGGL(k_w3gemm, dim3(E / 64), dim3(256), 0, stream,
                           h2b, w3bs, Wq, E);
        hipLaunchKernelGGL(k_gather_em, dim3(N), dim3(256), 0, stream,
                           off, up, sp, Wq, y0, y1, NP, aggs, aggv);
    } else if (ws_size >= need_B) {
        hipLaunchKernelGGL(k_mlp_wp, dim3((E + 255) / 256, 4), dim3(256), 0, stream,
                           rb, elist, w0T, w1T, w2T, w3T, Wp, E);
        hipLaunchKernelGGL(k_gather_wg, dim3(N), dim3(512), 0, stream,
                           off, elist, snd, evec, Wp, E, y0, y1, NP, aggs, aggv);
    } else {
        hipLaunchKernelGGL(k_mlp, dim3((E + 255) / 256), dim3(256), 0, stream,
                           rb, w0T, w1T, w2T, (float*)big, E);
        hipLaunchKernelGGL(k_gather_h2, dim3(N), dim3(512), 0, stream,
                           off, elist, snd, evec, (const float*)big, w3T,
                           y0, y1, NP, aggs, aggv);
    }

    hipLaunchKernelGGL(k_node_out, dim3(N / 4), dim3(256), 0, stream,
                       aggs, aggv, xs, xv, W20, W21, Wsk0, Wsk1, species,
                       (float*)d_out, N);
}

// Round 13
// 274.760 us; speedup vs baseline: 2.3237x; 1.2670x over previous
//
#include <hip/hip_runtime.h>
#include <math.h>

#define CC 128
#define HH 64
#define RBD 8
#define WDIM 512

typedef __attribute__((ext_vector_type(8))) short short8v;
typedef __attribute__((ext_vector_type(4))) float f32x4;

__device__ __forceinline__ float silu_f(float x) {
    return x / (1.0f + __expf(-x));
}

__device__ __forceinline__ unsigned short f2bf(float x) {
    unsigned int b = __float_as_uint(x);
    unsigned int r = (b + 0x7FFFu + ((b >> 16) & 1u)) >> 16;
    return (unsigned short)r;
}

__device__ __forceinline__ float bf2f(unsigned short u) {
    return __uint_as_float(((unsigned int)u) << 16);
}

// ---------------- prep: transposed weights (tier B/C) + MFMA fragment tables ----
// w3bs[((t*2+ch)*64+lane)*8+j] = w3[ch*32+8*(lane>>4)+j][t*16+(lane&15)]
// w0b [t][lane][j]: k=8*(lane>>4)+j (0 if k>=8), col=t*16+(lane&15)   (t=0..3)
// w1b/w2b [(ks*4+t)][lane][j]: k=ks*32+8*(lane>>4)+j, col=t*16+(lane&15)
__global__ void k_prep(const float* __restrict__ w0, const float* __restrict__ w1,
                       const float* __restrict__ w2, const float* __restrict__ w3,
                       float* __restrict__ w0T, float* __restrict__ w1T,
                       float* __restrict__ w2T, float* __restrict__ w3T,
                       unsigned short* __restrict__ w3bs,
                       unsigned short* __restrict__ w0b,
                       unsigned short* __restrict__ w1b,
                       unsigned short* __restrict__ w2b) {
    int i = blockIdx.x * blockDim.x + threadIdx.x;
    if (i < 64 * 8) { int m = i / 8, k = i % 8; w0T[i] = w0[k * 64 + m]; }
    if (i < 64 * 64) { int m = i / 64, k = i % 64; w1T[i] = w1[k * 64 + m]; w2T[i] = w2[k * 64 + m]; }
    if (i < 512 * 64) { int j = i / 64, k = i % 64; w3T[i] = w3[k * 512 + j]; }
    if (i < 32768) {
        int t = i >> 10, ch = (i >> 9) & 1, lane = (i >> 3) & 63, j = i & 7;
        int k = ch * 32 + 8 * (lane >> 4) + j;
        int n = t * 16 + (lane & 15);
        w3bs[i] = f2bf(w3[k * 512 + n]);
    }
    if (i < 2048) {
        int t = i >> 9, lane = (i >> 3) & 63, j = i & 7;
        int k = 8 * (lane >> 4) + j;
        int col = t * 16 + (lane & 15);
        w0b[i] = (k < RBD) ? f2bf(w0[k * 64 + col]) : (unsigned short)0;
    }
    if (i < 4096) {
        int f = i >> 9, lane = (i >> 3) & 63, j = i & 7;
        int ks = f >> 2, t = f & 3;
        int k = ks * 32 + 8 * (lane >> 4) + j;
        int col = t * 16 + (lane & 15);
        w1b[i] = f2bf(w1[k * 64 + col]);
        w2b[i] = f2bf(w2[k * 64 + col]);
    }
}

// ---------------- CSR build ----------------
__global__ void k_hist(const int* __restrict__ rcv, int* __restrict__ deg, int E_) {
    int e = blockIdx.x * blockDim.x + threadIdx.x;
    if (e < E_) atomicAdd(&deg[rcv[e]], 1);
}

__global__ __launch_bounds__(1024) void k_scan(const int* __restrict__ deg,
                                               int* __restrict__ off, int N) {
    __shared__ int s[1024];
    int t = threadIdx.x;
    int b = t * 4;
    int a0 = (b + 0 < N) ? deg[b + 0] : 0;
    int a1 = (b + 1 < N) ? deg[b + 1] : 0;
    int a2 = (b + 2 < N) ? deg[b + 2] : 0;
    int a3 = (b + 3 < N) ? deg[b + 3] : 0;
    int part = a0 + a1 + a2 + a3;
    s[t] = part;
    __syncthreads();
    for (int d = 1; d < 1024; d <<= 1) {
        int v = (t >= d) ? s[t - d] : 0;
        __syncthreads();
        s[t] += v;
        __syncthreads();
    }
    int excl = s[t] - part;
    if (b + 0 <= N) off[b + 0] = excl;
    if (b + 1 <= N) off[b + 1] = excl + a0;
    if (b + 2 <= N) off[b + 2] = excl + a0 + a1;
    if (b + 3 <= N) off[b + 3] = excl + a0 + a1 + a2;
}

__global__ void k_scatter(const int* __restrict__ rcv, const int* __restrict__ off,
                          int* __restrict__ cur, int* __restrict__ elist, int E_) {
    int e = blockIdx.x * blockDim.x + threadIdx.x;
    if (e < E_) {
        int r = rcv[e];
        int p = atomicAdd(&cur[r], 1);
        elist[off[r] + p] = e;
    }
}

// ---------------- edge meta: permuted unit vectors + senders ----------------
__global__ void k_emeta(const int* __restrict__ elist, const int* __restrict__ snd,
                        const float* __restrict__ evec,
                        float4* __restrict__ up, int* __restrict__ sp, int E_) {
    int p = blockIdx.x * blockDim.x + threadIdx.x;
    if (p >= E_) return;
    int e = elist[p];
    float e0 = evec[(size_t)e * 3 + 0];
    float e1 = evec[(size_t)e * 3 + 1];
    float e2 = evec[(size_t)e * 3 + 2];
    float rn = sqrtf(e0 * e0 + e1 * e1 + e2 * e2);
    float inv = 1.0f / fmaxf(rn, 1e-12f);
    up[p] = make_float4(e0 * inv, e1 * inv, e2 * inv, 0.f);
    sp[p] = snd[e];
}

// ---------------- node linear (planar y1: [3][N][C]) ----------------
__global__ __launch_bounds__(128) void k_node_lin(
    const float* __restrict__ xs, const float* __restrict__ xv,
    const float* __restrict__ W10, const float* __restrict__ W11,
    float* __restrict__ y0, float* __restrict__ y1, int N) {
    const int d = threadIdx.x;
    const int n0 = blockIdx.x * 4;
    const int NP = N * CC;
    const float inv_c = 0.08838834764831845f;
    float a0[4] = {0.f, 0.f, 0.f, 0.f};
    float av[4][3] = {};
    #pragma unroll 4
    for (int c = 0; c < CC; c++) {
        float w10 = W10[c * CC + d];
        float w11 = W11[c * CC + d];
        #pragma unroll
        for (int n = 0; n < 4; n++) {
            a0[n] += xs[(n0 + n) * CC + c] * w10;
            #pragma unroll
            for (int i = 0; i < 3; i++)
                av[n][i] += xv[((n0 + n) * CC + c) * 3 + i] * w11;
        }
    }
    #pragma unroll
    for (int n = 0; n < 4; n++) {
        y0[(n0 + n) * CC + d] = a0[n] * inv_c;
        #pragma unroll
        for (int i = 0; i < 3; i++)
            y1[i * NP + (n0 + n) * CC + d] = av[n][i] * inv_c;
    }
}

// ---------------- shared VALU MLP body (tiers B/C) ----------------
__device__ __forceinline__ void layer64(const float4* a, float4* b,
                                        const float* __restrict__ W) {
    #pragma unroll
    for (int m = 0; m < 16; m++) {
        float s0 = 0.f, s1 = 0.f, s2 = 0.f, s3 = 0.f;
        const float* w0p = W + (4 * m + 0) * 64;
        const float* w1p = W + (4 * m + 1) * 64;
        const float* w2p = W + (4 * m + 2) * 64;
        const float* w3p = W + (4 * m + 3) * 64;
        #pragma unroll
        for (int k = 0; k < 16; k++) {
            float4 av = a[k];
            s0 += av.x * w0p[4 * k + 0] + av.y * w0p[4 * k + 1] + av.z * w0p[4 * k + 2] + av.w * w0p[4 * k + 3];
            s1 += av.x * w1p[4 * k + 0] + av.y * w1p[4 * k + 1] + av.z * w1p[4 * k + 2] + av.w * w1p[4 * k + 3];
            s2 += av.x * w2p[4 * k + 0] + av.y * w2p[4 * k + 1] + av.z * w2p[4 * k + 2] + av.w * w2p[4 * k + 3];
            s3 += av.x * w3p[4 * k + 0] + av.y * w3p[4 * k + 1] + av.z * w3p[4 * k + 2] + av.w * w3p[4 * k + 3];
        }
        b[m] = make_float4(silu_f(s0), silu_f(s1), silu_f(s2), silu_f(s3));
    }
}

__device__ __forceinline__ void mlp_body(
    const float* __restrict__ rb, int e,
    const float* __restrict__ w0T, const float* __restrict__ w1T,
    const float* __restrict__ w2T, float4* a) {
    float rbv[RBD];
    #pragma unroll
    for (int k = 0; k < RBD; k++) rbv[k] = rb[(size_t)e * RBD + k];
    float4 b[16];
    #pragma unroll
    for (int m = 0; m < 16; m++) {
        float s0 = 0.f, s1 = 0.f, s2 = 0.f, s3 = 0.f;
        #pragma unroll
        for (int k = 0; k < RBD; k++) {
            float rv = rbv[k];
            s0 += rv * w0T[(4 * m + 0) * RBD + k];
            s1 += rv * w0T[(4 * m + 1) * RBD + k];
            s2 += rv * w0T[(4 * m + 2) * RBD + k];
            s3 += rv * w0T[(4 * m + 3) * RBD + k];
        }
        a[m] = make_float4(silu_f(s0), silu_f(s1), silu_f(s2), silu_f(s3));
    }
    layer64(a, b, w1T);
    layer64(b, a, w2T);   // a holds h2
}

// ---------------- tier A: fused MFMA MLP + w3 GEMM -> pair-packed Wq ---------
// Wave = 16 edges. Each MLP layer = mfma_f32_16x16x32_bf16 with pre-swizzled
// B fragments; f32 silu on accumulators; bf16 h staged in padded LDS [16][72]
// (row stride 144B -> conflict-light ds_read_b128) to convert C/D layout into
// the next layer's A-fragment layout. Final h2 feeds w3 GEMM directly (no
// global h2 round-trip). Requires E % 64 == 0 (grid exact, no guards).
__global__ __launch_bounds__(256) void k_mlpw3(
    const float* __restrict__ rb, const int* __restrict__ elist,
    const unsigned short* __restrict__ w0b, const unsigned short* __restrict__ w1b,
    const unsigned short* __restrict__ w2b, const unsigned short* __restrict__ w3bs,
    unsigned int* __restrict__ Wq, int E_) {
    const int lane = threadIdx.x & 63;
    const int wv = threadIdx.x >> 6;
    const int rbk = blockIdx.x * 4 + wv;   // row-block of 16 edges
    const int col = lane & 15;             // N index within tile / A-row (edge)
    const int grp = lane >> 4;

    __shared__ unsigned short hbuf[4][16][72];

    // ---- L0: rb (16x8, K-padded to 32) @ w0 (8x64) ----
    short8v a0 = (short8v){0, 0, 0, 0, 0, 0, 0, 0};
    if (grp == 0) {
        int e = elist[rbk * 16 + col];
        const float* rp = rb + (size_t)e * RBD;
        #pragma unroll
        for (int j = 0; j < RBD; j++) a0[j] = (short)f2bf(rp[j]);
    }
    f32x4 acc[4];
    {
        const unsigned short* bp = w0b + (size_t)lane * 8;
        #pragma unroll
        for (int t = 0; t < 4; t++) {
            short8v b = *(const short8v*)(bp + (size_t)t * 512);
            acc[t] = __builtin_amdgcn_mfma_f32_16x16x32_bf16(
                a0, b, (f32x4){0.f, 0.f, 0.f, 0.f}, 0, 0, 0);
        }
    }
    #pragma unroll
    for (int t = 0; t < 4; t++)
        #pragma unroll
        for (int r = 0; r < 4; r++)
            hbuf[wv][grp * 4 + r][t * 16 + col] = f2bf(silu_f(acc[t][r]));
    __syncthreads();

    // ---- L1: h0 (16x64) @ w1 (64x64) ----
    {
        short8v aA = *(const short8v*)&hbuf[wv][col][8 * grp];
        short8v aB = *(const short8v*)&hbuf[wv][col][32 + 8 * grp];
        const unsigned short* bp = w1b + (size_t)lane * 8;
        #pragma unroll
        for (int t = 0; t < 4; t++) {
            short8v b0 = *(const short8v*)(bp + (size_t)(0 + t) * 512);
            short8v b1 = *(const short8v*)(bp + (size_t)(4 + t) * 512);
            f32x4 c = __builtin_amdgcn_mfma_f32_16x16x32_bf16(
                aA, b0, (f32x4){0.f, 0.f, 0.f, 0.f}, 0, 0, 0);
            acc[t] = __builtin_amdgcn_mfma_f32_16x16x32_bf16(aB, b1, c, 0, 0, 0);
        }
    }
    __syncthreads();
    #pragma unroll
    for (int t = 0; t < 4; t++)
        #pragma unroll
        for (int r = 0; r < 4; r++)
            hbuf[wv][grp * 4 + r][t * 16 + col] = f2bf(silu_f(acc[t][r]));
    __syncthreads();

    // ---- L2: h1 @ w2 ----
    {
        short8v aA = *(const short8v*)&hbuf[wv][col][8 * grp];
        short8v aB = *(const short8v*)&hbuf[wv][col][32 + 8 * grp];
        const unsigned short* bp = w2b + (size_t)lane * 8;
        #pragma unroll
        for (int t = 0; t < 4; t++) {
            short8v b0 = *(const short8v*)(bp + (size_t)(0 + t) * 512);
            short8v b1 = *(const short8v*)(bp + (size_t)(4 + t) * 512);
            f32x4 c = __builtin_amdgcn_mfma_f32_16x16x32_bf16(
                aA, b0, (f32x4){0.f, 0.f, 0.f, 0.f}, 0, 0, 0);
            acc[t] = __builtin_amdgcn_mfma_f32_16x16x32_bf16(aB, b1, c, 0, 0, 0);
        }
    }
    __syncthreads();
    #pragma unroll
    for (int t = 0; t < 4; t++)
        #pragma unroll
        for (int r = 0; r < 4; r++)
            hbuf[wv][grp * 4 + r][t * 16 + col] = f2bf(silu_f(acc[t][r]));
    __syncthreads();

    // ---- w3 GEMM: h2 (16x64) @ w3 (64x512) -> Wq ----
    short8v A0 = *(const short8v*)&hbuf[wv][col][8 * grp];
    short8v A1 = *(const short8v*)&hbuf[wv][col][32 + 8 * grp];

    f32x4 wacc[32];
    #pragma unroll
    for (int t = 0; t < 32; t++) wacc[t] = (f32x4){0.f, 0.f, 0.f, 0.f};

    const unsigned short* bbase = w3bs + (size_t)lane * 8;
    #pragma unroll
    for (int t = 0; t < 32; t++) {
        short8v b0 = *(const short8v*)(bbase + (size_t)(t * 2 + 0) * 512);
        short8v b1 = *(const short8v*)(bbase + (size_t)(t * 2 + 1) * 512);
        wacc[t] = __builtin_amdgcn_mfma_f32_16x16x32_bf16(A0, b0, wacc[t], 0, 0, 0);
        wacc[t] = __builtin_amdgcn_mfma_f32_16x16x32_bf16(A1, b1, wacc[t], 0, 0, 0);
    }

    const int rowq = grp * 4;
    const int jbase = rbk * 16 + rowq;
    #pragma unroll
    for (int t = 0; t < 16; t++) {
        #pragma unroll
        for (int rr = 0; rr < 4; rr++) {
            unsigned lo = f2bf(wacc[t][rr]);
            unsigned hi = f2bf(wacc[t + 16][rr]);
            Wq[(size_t)(jbase + rr) * 256 + t * 16 + col] = lo | (hi << 16);
        }
    }
}

// ---------------- tier A gather: edge-major (merged halves) ----------------
__global__ __launch_bounds__(256, 4) void k_gather_em(
    const int* __restrict__ off, const float4* __restrict__ up,
    const int* __restrict__ sp, const unsigned int* __restrict__ Wq,
    const float* __restrict__ y0, const float* __restrict__ y1, int NP,
    float* __restrict__ agg_s, float* __restrict__ agg_v) {
    const int r = blockIdx.x;
    const int tid = threadIdx.x;
    const int half = tid >> 7;
    const int c = tid & 127;
    const int start = off[r];
    const int end = off[r + 1];

    float accs = 0.f, av0 = 0.f, av1 = 0.f, av2 = 0.f;
    const float SQ3 = 1.7320508075688772f;

    #pragma unroll 2
    for (int j = start; j < end; j++) {
        unsigned wq = Wq[(size_t)j * 256 + tid];
        float4 u = up[j];
        int s = __builtin_amdgcn_readfirstlane(sp[j]);
        float wa = bf2f((unsigned short)(wq & 0xFFFFu));
        float wb = bf2f((unsigned short)(wq >> 16));
        if (half == 0) {
            float f = y0[(size_t)s * CC + c];
            accs += f * wa;
            float bb = f * wb * SQ3;
            av0 += bb * u.x; av1 += bb * u.y; av2 += bb * u.z;
        } else {
            float f0 = y1[0 * NP + s * CC + c];
            float f1 = y1[1 * NP + s * CC + c];
            float f2 = y1[2 * NP + s * CC + c];
            accs += (f0 * u.x + f1 * u.y + f2 * u.z) * wa;
            av0 += f0 * wb; av1 += f1 * wb; av2 += f2 * wb;
        }
    }

    agg_s[(size_t)r * 256 + tid] = accs;
    float* o = agg_v + ((size_t)r * 256 + tid) * 3;
    o[0] = av0; o[1] = av1; o[2] = av2;
}

// ---------------- tier B: VALU writer (grouped layout) + its gather ----------------
__global__ __launch_bounds__(256) void k_mlp_wp(
    const float* __restrict__ rb, const int* __restrict__ elist,
    const float* __restrict__ w0T, const float* __restrict__ w1T,
    const float* __restrict__ w2T, const float* __restrict__ w3T,
    unsigned short* __restrict__ Wp, int E_) {
    int p = blockIdx.x * blockDim.x + threadIdx.x;
    if (p >= E_) return;
    int e = elist[p];
    const int c0 = blockIdx.y * 128;

    float4 a[16];
    mlp_body(rb, e, w0T, w1T, w2T, a);

    const size_t E4 = (size_t)E_ * 4;
    for (int c = c0; c < c0 + 128; c += 8) {
        float s[8];
        #pragma unroll
        for (int q = 0; q < 8; q++) {
            const float* rp = w3T + (size_t)(c + q) * 64;
            float t0 = 0.f, t1 = 0.f, t2 = 0.f, t3 = 0.f;
            #pragma unroll
            for (int k = 0; k < 16; k++) {
                float4 h = a[k];
                t0 += h.x * rp[4 * k + 0];
                t1 += h.y * rp[4 * k + 1];
                t2 += h.z * rp[4 * k + 2];
                t3 += h.w * rp[4 * k + 3];
            }
            s[q] = (t0 + t1) + (t2 + t3);
        }
        ushort4 pk0 = make_ushort4(f2bf(s[0]), f2bf(s[1]), f2bf(s[2]), f2bf(s[3]));
        ushort4 pk1 = make_ushort4(f2bf(s[4]), f2bf(s[5]), f2bf(s[6]), f2bf(s[7]));
        *(ushort4*)(Wp + (size_t)(c >> 2) * E4 + (size_t)p * 4) = pk0;
        *(ushort4*)(Wp + (size_t)((c >> 2) + 1) * E4 + (size_t)p * 4) = pk1;
    }
}

__global__ __launch_bounds__(512, 2) void k_gather_wg(
    const int* __restrict__ off, const int* __restrict__ elist,
    const int* __restrict__ snd, const float* __restrict__ evec,
    const unsigned short* __restrict__ Wp, int E_,
    const float* __restrict__ y0, const float* __restrict__ y1, int NP,
    float* __restrict__ agg_s, float* __restrict__ agg_v) {
    const int r = blockIdx.x;
    const int tid = threadIdx.x;
    const int part = tid >> 7;
    const int c = tid & 127;

    const int start = off[r];
    const int end = off[r + 1];

    const unsigned short* __restrict__ wstream =
        Wp + (size_t)(tid >> 2) * ((size_t)E_ * 4) + (tid & 3);

    float acc0 = 0.f, acc1 = 0.f, acc2 = 0.f;
    const float SQ3 = 1.7320508075688772f;

    #pragma unroll 2
    for (int j = start; j < end; j++) {
        int e = elist[j];
        e = __builtin_amdgcn_readfirstlane(e);
        int s = snd[e];
        s = __builtin_amdgcn_readfirstlane(s);

        float e0 = evec[(size_t)e * 3 + 0];
        float e1 = evec[(size_t)e * 3 + 1];
        float e2 = evec[(size_t)e * 3 + 2];
        float rn = sqrtf(e0 * e0 + e1 * e1 + e2 * e2);
        float inv = 1.0f / fmaxf(rn, 1e-12f);
        float ux = e0 * inv, uy = e1 * inv, uz = e2 * inv;

        float w = bf2f(wstream[(size_t)j * 4]);

        if (part == 0) {
            acc0 += y0[(size_t)s * CC + c] * w;
        } else if (part == 1) {
            float f = y1[0 * NP + s * CC + c] * ux
                    + y1[1 * NP + s * CC + c] * uy
                    + y1[2 * NP + s * CC + c] * uz;
            acc0 += f * w;
        } else if (part == 2) {
            float bb = y0[(size_t)s * CC + c] * w * SQ3;
            acc0 += bb * ux; acc1 += bb * uy; acc2 += bb * uz;
        } else {
            acc0 += y1[0 * NP + s * CC + c] * w;
            acc1 += y1[1 * NP + s * CC + c] * w;
            acc2 += y1[2 * NP + s * CC + c] * w;
        }
    }

    if (part == 0) {
        agg_s[(size_t)r * 2 * CC + c] = acc0;
    } else if (part == 1) {
        agg_s[(size_t)r * 2 * CC + CC + c] = acc0;
    } else if (part == 2) {
        float* o = agg_v + ((size_t)r * 2 * CC + c) * 3;
        o[0] = acc0; o[1] = acc1; o[2] = acc2;
    } else {
        float* o = agg_v + ((size_t)r * 2 * CC + CC + c) * 3;
        o[0] = acc0; o[1] = acc1; o[2] = acc2;
    }
}

// ---------------- tier C: f32 h2 fallback ----------------
__global__ void k_mlp(const float* __restrict__ rb,
                      const float* __restrict__ w0T, const float* __restrict__ w1T,
                      const float* __restrict__ w2T,
                      float* __restrict__ h2, int E_) {
    int e = blockIdx.x * blockDim.x + threadIdx.x;
    if (e >= E_) return;
    float4 a[16];
    mlp_body(rb, e, w0T, w1T, w2T, a);
    float4* out = (float4*)(h2 + (size_t)e * HH);
    #pragma unroll
    for (int q = 0; q < 16; q++) out[q] = a[q];
}

__global__ __launch_bounds__(512, 1) void k_gather_h2(
    const int* __restrict__ off, const int* __restrict__ elist,
    const int* __restrict__ snd, const float* __restrict__ evec,
    const float* __restrict__ h2, const float* __restrict__ w3T,
    const float* __restrict__ y0, const float* __restrict__ y1, int NP,
    float* __restrict__ agg_s, float* __restrict__ agg_v) {
    const int r = blockIdx.x;
    const int tid = threadIdx.x;
    const int part = tid >> 7;
    const int c = tid & 127;

    const float4* wp = (const float4*)(w3T + (size_t)tid * 64);
    const int start = off[r];
    const int end = off[r + 1];

    float acc0 = 0.f, acc1 = 0.f, acc2 = 0.f;
    const float SQ3 = 1.7320508075688772f;

    for (int j = start; j < end; j++) {
        int e = elist[j];
        e = __builtin_amdgcn_readfirstlane(e);
        int s = snd[e];
        s = __builtin_amdgcn_readfirstlane(s);

        float e0 = evec[(size_t)e * 3 + 0];
        float e1 = evec[(size_t)e * 3 + 1];
        float e2 = evec[(size_t)e * 3 + 2];
        float rn = sqrtf(e0 * e0 + e1 * e1 + e2 * e2);
        float inv = 1.0f / fmaxf(rn, 1e-12f);
        float ux = e0 * inv, uy = e1 * inv, uz = e2 * inv;

        const float4* __restrict__ hp = (const float4*)(h2 + ((size_t)e << 6));
        float ws0 = 0.f, ws1 = 0.f, ws2 = 0.f, ws3 = 0.f;
        #pragma unroll
        for (int k = 0; k < 16; k++) {
            float4 h = hp[k];
            float4 wv = wp[k];
            ws0 += h.x * wv.x; ws1 += h.y * wv.y; ws2 += h.z * wv.z; ws3 += h.w * wv.w;
        }
        float w = (ws0 + ws1) + (ws2 + ws3);

        if (part == 0) {
            acc0 += y0[(size_t)s * CC + c] * w;
        } else if (part == 1) {
            float f = y1[0 * NP + s * CC + c] * ux
                    + y1[1 * NP + s * CC + c] * uy
                    + y1[2 * NP + s * CC + c] * uz;
            acc0 += f * w;
        } else if (part == 2) {
            float bb = y0[(size_t)s * CC + c] * w * SQ3;
            acc0 += bb * ux; acc1 += bb * uy; acc2 += bb * uz;
        } else {
            acc0 += y1[0 * NP + s * CC + c] * w;
            acc1 += y1[1 * NP + s * CC + c] * w;
            acc2 += y1[2 * NP + s * CC + c] * w;
        }
    }

    if (part == 0) {
        agg_s[(size_t)r * 2 * CC + c] = acc0;
    } else if (part == 1) {
        agg_s[(size_t)r * 2 * CC + CC + c] = acc0;
    } else if (part == 2) {
        float* o = agg_v + ((size_t)r * 2 * CC + c) * 3;
        o[0] = acc0; o[1] = acc1; o[2] = acc2;
    } else {
        float* o = agg_v + ((size_t)r * 2 * CC + CC + c) * 3;
        o[0] = acc0; o[1] = acc1; o[2] = acc2;
    }
}

// ---------------- node output ----------------
__global__ __launch_bounds__(256) void k_node_out(
    const float* __restrict__ agg_s, const float* __restrict__ agg_v,
    const float* __restrict__ xs, const float* __restrict__ xv,
    const float* __restrict__ W20, const float* __restrict__ W21,
    const float* __restrict__ Wsk0, const float* __restrict__ Wsk1,
    const int* __restrict__ species,
    float* __restrict__ out, int N) {
    const int tid = threadIdx.x;
    const int n0 = blockIdx.x * 4;

    __shared__ float as_l[4 * 256];
    __shared__ float av_l[4 * 768];
    __shared__ float xs_l[4 * 128];
    __shared__ float xv_l[4 * 384];
    __shared__ float s_l[4 * 256];

    for (int i = tid; i < 4 * 256; i += 256) as_l[i] = agg_s[(size_t)n0 * 256 + i];
    for (int i = tid; i < 4 * 768; i += 256) av_l[i] = agg_v[(size_t)n0 * 768 + i];
    for (int i = tid; i < 4 * 128; i += 256) xs_l[i] = xs[(size_t)n0 * 128 + i];
    for (int i = tid; i < 4 * 384; i += 256) xv_l[i] = xv[(size_t)n0 * 384 + i];
    int sp[4];
    #pragma unroll
    for (int n = 0; n < 4; n++) sp[n] = species[n0 + n];
    __syncthreads();

    const float k_mat = 0.17677669529663687f * 0.0625f; // inv_nb * inv_2c
    const float inv_c = 0.08838834764831845f;

    {
        const int d = tid;
        float am[4] = {0.f, 0.f, 0.f, 0.f};
        for (int cc = 0; cc < 256; cc++) {
            float w = W20[cc * 256 + d];
            #pragma unroll
            for (int n = 0; n < 4; n++) am[n] += as_l[n * 256 + cc] * w;
        }
        float ak[4] = {0.f, 0.f, 0.f, 0.f};
        for (int cc = 0; cc < 128; cc++) {
            #pragma unroll
            for (int n = 0; n < 4; n++) {
                float w = Wsk0[((size_t)sp[n] * 128 + cc) * 256 + d];
                ak[n] += xs_l[n * 128 + cc] * w;
            }
        }
        #pragma unroll
        for (int n = 0; n < 4; n++) s_l[n * 256 + d] = am[n] * k_mat + ak[n] * inv_c;
    }
    __syncthreads();

    if (tid < 128) {
        #pragma unroll
        for (int n = 0; n < 4; n++)
            out[(size_t)(n0 + n) * 512 + tid] = silu_f(s_l[n * 256 + tid]);
    }

    {
        const int d = tid & 127;
        const int half = tid >> 7;
        int spB[2];
        #pragma unroll
        for (int nn = 0; nn < 2; nn++) spB[nn] = species[n0 + half * 2 + nn];

        float am[2][3] = {};
        for (int cc = 0; cc < 256; cc++) {
            float w = W21[cc * 128 + d];
            #pragma unroll
            for (int nn = 0; nn < 2; nn++) {
                int n = half * 2 + nn;
                #pragma unroll
                for (int i = 0; i < 3; i++) am[nn][i] += av_l[n * 768 + cc * 3 + i] * w;
            }
        }
        float ak[2][3] = {};
        for (int cc = 0; cc < 128; cc++) {
            #pragma unroll
            for (int nn = 0; nn < 2; nn++) {
                int n = half * 2 + nn;
                float w = Wsk1[((size_t)spB[nn] * 128 + cc) * 128 + d];
                #pragma unroll
                for (int i = 0; i < 3; i++) ak[nn][i] += xv_l[n * 384 + cc * 3 + i] * w;
            }
        }
        #pragma unroll
        for (int nn = 0; nn < 2; nn++) {
            int n = half * 2 + nn;
            float g = silu_f(s_l[n * 256 + 128 + d]);
            #pragma unroll
            for (int i = 0; i < 3; i++)
                out[(size_t)(n0 + n) * 512 + 128 + d * 3 + i] =
                    (am[nn][i] * k_mat + ak[nn][i] * inv_c) * g;
        }
    }
}

extern "C" void kernel_launch(void* const* d_in, const int* in_sizes, int n_in,
                              void* d_out, int out_size, void* d_ws, size_t ws_size,
                              hipStream_t stream) {
    const float* xs   = (const float*)d_in[0];
    const float* xv   = (const float*)d_in[1];
    const float* evec = (const float*)d_in[2];
    const float* rb   = (const float*)d_in[3];
    const float* W10  = (const float*)d_in[4];
    const float* W11  = (const float*)d_in[5];
    const float* w0   = (const float*)d_in[6];
    const float* w1   = (const float*)d_in[7];
    const float* w2   = (const float*)d_in[8];
    const float* w3   = (const float*)d_in[9];
    const float* W20  = (const float*)d_in[10];
    const float* W21  = (const float*)d_in[11];
    const float* Wsk0 = (const float*)d_in[12];
    const float* Wsk1 = (const float*)d_in[13];
    const int* species = (const int*)d_in[14];
    const int* snd = (const int*)d_in[15];
    const int* rcv = (const int*)d_in[16];

    const int N = in_sizes[0] / CC;   // 4000
    const int E = in_sizes[2] / 3;    // 128000
    const int NP = N * CC;

    float* ws   = (float*)d_ws;
    float* y0   = ws;
    float* y1   = y0 + (size_t)N * CC;
    float* aggs = y1 + (size_t)N * CC * 3;
    float* aggv = aggs + (size_t)N * 2 * CC;
    float* w0T  = aggv + (size_t)N * 2 * CC * 3;
    float* w1T  = w0T + 64 * 8;
    float* w2T  = w1T + 64 * 64;
    float* w3T  = w2T + 64 * 64;
    unsigned short* w3bs = (unsigned short*)(w3T + 512 * 64);   // 32768 bf16
    unsigned short* w0b  = w3bs + 32768;                        // 2048
    unsigned short* w1b  = w0b + 2048;                          // 4096
    unsigned short* w2b  = w1b + 4096;                          // 4096
    int*   deg  = (int*)(w2b + 4096);
    int*   cur  = deg + 4096;
    int*   off  = cur + 4096;
    int*   elist = off + 4160;
    float4* up  = (float4*)(elist + E);      // E float4 (16B-aligned)
    int*   sp   = (int*)(up + E);            // E ints
    void*  big  = (void*)(sp + E);

    size_t base_bytes = (size_t)((char*)big - (char*)d_ws);
    size_t wq_bytes   = (size_t)E * 256 * sizeof(unsigned int);   // == E*512*2B
    size_t need_A = base_bytes + wq_bytes;
    size_t need_B = base_bytes + (size_t)E * WDIM * sizeof(unsigned short);

    unsigned int*   Wq  = (unsigned int*)big;
    unsigned short* Wp  = (unsigned short*)big;

    hipMemsetAsync(deg, 0, 2 * 4096 * sizeof(int), stream);
    hipLaunchKernelGGL(k_hist, dim3((E + 255) / 256), dim3(256), 0, stream, rcv, deg, E);
    hipLaunchKernelGGL(k_scan, dim3(1), dim3(1024), 0, stream, deg, off, N);
    hipLaunchKernelGGL(k_scatter, dim3((E + 255) / 256), dim3(256), 0, stream,
                       rcv, off, cur, elist, E);
    hipLaunchKernelGGL(k_prep, dim3(128), dim3(256), 0, stream,
                       w0, w1, w2, w3, w0T, w1T, w2T, w3T, w3bs, w0b, w1b, w2b);
    hipLaunchKernelGGL(k_node_lin, dim3(N / 4), dim3(128), 0, stream,
                       xs, xv, W10, W11, y0, y1, N);

    if (ws_size >= need_A && (E % 64) == 0) {
        hipLaunchKernelGGL(k_emeta, dim3((E + 255) / 256), dim3(256), 0, stream,
                           elist, snd, evec, up, sp, E);
        hipLaunchKernelGGL(k_mlpw3, dim3(E / 64), dim3(256), 0, stream,
                           rb, elist, w0b, w1b, w2b, w3bs, Wq, E);
        hipLaunchKernelGGL(k_gather_em, dim3(N), dim3(256), 0, stream,
                           off, up, sp, Wq, y0, y1, NP, aggs, aggv);
    } else if (ws_size >= need_B) {
        hipLaunchKernelGGL(k_mlp_wp, dim3((E + 255) / 256, 4), dim3(256), 0, stream,
                           rb, elist, w0T, w1T, w2T, w3T, Wp, E);
        hipLaunchKernelGGL(k_gather_wg, dim3(N), dim3(512), 0, stream,
                           off, elist, snd, evec, Wp, E, y0, y1, NP, aggs, aggv);
    } else {
        hipLaunchKernelGGL(k_mlp, dim3((E + 255) / 256), dim3(256), 0, stream,
                           rb, w0T, w1T, w2T, (float*)big, E);
        hipLaunchKernelGGL(k_gather_h2, dim3(N), dim3(512), 0, stream,
                           off, elist, snd, evec, (const float*)big, w3T,
                           y0, y1, NP, aggs, aggv);
    }

    hipLaunchKernelGGL(k_node_out, dim3(N / 4), dim3(256), 0, stream,
                       aggs, aggv, xs, xv, W20, W21, Wsk0, Wsk1, species,
                       (float*)d_out, N);
}